// Round 7
// baseline (338.085 us; speedup 1.0000x reference)
//
#include <hip/hip_runtime.h>
#include <math.h>

#define BATCH 32768
#define LW    200
#define CIN   6
#define KSZ   5
#define FLAT  196     // LW - KSZ + 1
#define NH1   50
#define NH2   30
#define NOUT  15
#define XROW  (CIN * LW)   // 1200 floats per batch row

// Round-13: (a) K1 keeps the no-LDS per-lane register conv, but consumes
// conv outputs in PERMUTED stride-4 order so the first 7 FMA groups touch
// all 8 float4 words of the channel window -- forcing the compiler to keep
// the full channel's 8 loads in flight (round-12's VGPR=60 proved it was
// shrinking the in-flight window below the intended 2-deep prefetch).
// (b) K2 was the hidden half: bench ~= 2*(K1+K2)+40 across rounds -> K2
// ~45 us at 0.5 waves/SIMD (512 waves total, half the SIMDs idle). New K2:
// QUAD-SPLIT -- 4 lanes per batch, 2048 waves = 2/SIMD everywhere; roles
// load slice-shares for all 50 k (<=100 independent loads), __shfl_xor quad
// reduce, fc2/fc3/Jacobi computed redundantly per quad (those SIMDs were
// idle anyway), role-striped output writes.

__device__ __forceinline__ float fget(const float4 (&a)[8], int i) {
    // i is compile-time constant under full unroll -> folds to a register ref
    const float4 v = a[i >> 2];
    const int m = i & 3;
    return m == 0 ? v.x : (m == 1 ? v.y : (m == 2 ? v.z : v.w));
}

// consume channel CH from window R in stride-4 permuted order:
// i = 0,4,8,12,16,20,24,1,5,...,27 -- first 7 iterations touch R[0..7],
// forcing all 8 loads of this channel to be resident before compute starts.
#define CONVSTEP(R, CH)                                        \
    _Pragma("unroll")                                          \
    for (int ii = 0; ii < 28; ++ii) {                          \
        const int i = (4 * ii) % 28 + (4 * ii) / 28;           \
        float aa = acc[i];                                     \
        aa = fmaf(fget(R, i + 0), w[CH][0], aa);               \
        aa = fmaf(fget(R, i + 1), w[CH][1], aa);               \
        aa = fmaf(fget(R, i + 2), w[CH][2], aa);               \
        aa = fmaf(fget(R, i + 3), w[CH][3], aa);               \
        aa = fmaf(fget(R, i + 4), w[CH][4], aa);               \
        acc[i] = aa;                                           \
    }

#define LOADCH(R, CH)                                          \
    _Pragma("unroll")                                          \
    for (int u = 0; u < 8; ++u)                                \
        R[u] = *(const float4*)(xb + (CH) * LW + 4 * u);

// ---------------- K1 primary: 7-way split, NS=28, no LDS ----------------
__global__ void __launch_bounds__(64)
conv_fc1_k7(const float* __restrict__ x,
            const float* __restrict__ cw, const float* __restrict__ cb,
            const float* __restrict__ w1, float* __restrict__ part)
{
    const int lane = threadIdx.x;
    const int bid  = blockIdx.x;
    // XCD-chunked remap: HW round-robins XCD = bid & 7; give XCD r the batch
    // groups [64r,64r+64) so all 7 slice-blocks of a group share r's L2.
    const int r  = bid & 7;
    const int q  = bid >> 3;              // 0 .. 64*7-1
    const int gq = q / 7;
    const int s  = q - gq * 7;            // slice 0..6
    const int g  = r * 64 + gq;           // batch group (64 batches)
    const int kstart = 28 * s;            // conv-output slice base (28s: f4-aligned)

    // conv weights / bias: wave-uniform -> SGPRs
    float w[CIN][KSZ];
#pragma unroll
    for (int c = 0; c < CIN; ++c)
#pragma unroll
        for (int k = 0; k < KSZ; ++k)
            w[c][k] = __int_as_float(
                __builtin_amdgcn_readfirstlane(__float_as_int(cw[c * KSZ + k])));
    const float bias = __int_as_float(
        __builtin_amdgcn_readfirstlane(__float_as_int(cb[0])));

    // per-lane row base: this lane's batch, window cols [kstart, kstart+32)
    const float* xb = x + (size_t)(g * 64 + lane) * XROW + kstart;

    float acc[28];
#pragma unroll
    for (int i = 0; i < 28; ++i) acc[i] = bias;

    float4 A[8], B[8];
    LOADCH(A, 0)
    LOADCH(B, 1)

    CONVSTEP(A, 0)
    LOADCH(A, 2)
    CONVSTEP(B, 1)
    LOADCH(B, 3)
    CONVSTEP(A, 2)
    LOADCH(A, 4)
    CONVSTEP(B, 3)
    LOADCH(B, 5)
    CONVSTEP(A, 4)
    CONVSTEP(B, 5)

    // ---- fc1 partials: two 25-col passes, 2-row pairing ----
    float* pb = part + (size_t)(s * NH1) * BATCH + (size_t)g * 64 + lane;
#pragma unroll
    for (int half = 0; half < 2; ++half) {
        const int j0 = half * 25;
        float h1p[25];
#pragma unroll
        for (int j = 0; j < 25; ++j) h1p[j] = 0.f;
#pragma unroll
        for (int ii = 0; ii < 28; ii += 2) {
            const float* wr0 = w1 + (size_t)(kstart + ii) * NH1 + j0;  // uniform -> s_load
            const float* wr1 = wr0 + NH1;
            float c0 = acc[ii], c1 = acc[ii + 1];
#pragma unroll
            for (int j = 0; j < 25; ++j)
                h1p[j] = fmaf(c1, wr1[j], fmaf(c0, wr0[j], h1p[j]));
        }
#pragma unroll
        for (int j = 0; j < 25; ++j)
            pb[(size_t)(j0 + j) * BATCH] = h1p[j];
    }
}

// ---------------- K1 fallbacks (smaller workspace; LDS-staged body) ----
template<int NS, int TB, int NLD, int TW, int NSPLIT>
__device__ __forceinline__ void conv_fc1_body(
    const float* __restrict__ x,
    const float* __restrict__ cw, const float* __restrict__ cb,
    const float* __restrict__ w1, float* __restrict__ part,
    float* __restrict__ tile)
{
    const int lane = threadIdx.x;
    const int bid  = blockIdx.x;
    const int r = bid & 7;
    const int q = bid >> 3;
    const int g = r * 64 + q / NSPLIT;
    const int s = q - (q / NSPLIT) * NSPLIT;
    const int kstart = NS * s;
    const int tbase  = TB * s;
    const int off    = kstart - tbase;

    float w[CIN][KSZ];
#pragma unroll
    for (int c = 0; c < CIN; ++c)
#pragma unroll
        for (int k = 0; k < KSZ; ++k)
            w[c][k] = __int_as_float(
                __builtin_amdgcn_readfirstlane(__float_as_int(cw[c * KSZ + k])));
    const float bias = __int_as_float(
        __builtin_amdgcn_readfirstlane(__float_as_int(cb[0])));

    int goff[NLD], loff[NLD];
#pragma unroll
    for (int u = 0; u < NLD; ++u) {
        int g4  = lane + 64 * u;
        int row = g4 / NLD;
        int c4  = g4 - row * NLD;
        goff[u] = row * XROW + 4 * c4;
        loff[u] = row * TW + 4 * c4;
    }
    const float* xw = x + (size_t)g * 64 * XROW + tbase;

    float acc[NS];
#pragma unroll
    for (int i = 0; i < NS; ++i) acc[i] = bias;

    float4 buf[NLD];
#pragma unroll
    for (int u = 0; u < NLD; ++u) buf[u] = *(const float4*)(xw + goff[u]);

#pragma unroll
    for (int ch = 0; ch < CIN; ++ch) {
#pragma unroll
        for (int u = 0; u < NLD; ++u) {
            float* dst = tile + loff[u];
            dst[0] = buf[u].x; dst[1] = buf[u].y; dst[2] = buf[u].z; dst[3] = buf[u].w;
        }
        if (ch + 1 < CIN) {
#pragma unroll
            for (int u = 0; u < NLD; ++u)
                buf[u] = *(const float4*)(xw + (ch + 1) * LW + goff[u]);
        }
        const float* row = tile + lane * TW + off;
        float x0 = row[0], x1 = row[1], x2 = row[2], x3 = row[3];
#pragma unroll
        for (int i = 0; i < NS; ++i) {
            float x4v = row[i + 4];
            float a = acc[i];
            a = fmaf(x0, w[ch][0], a);
            a = fmaf(x1, w[ch][1], a);
            a = fmaf(x2, w[ch][2], a);
            a = fmaf(x3, w[ch][3], a);
            a = fmaf(x4v, w[ch][4], a);
            acc[i] = a;
            x0 = x1; x1 = x2; x2 = x3; x3 = x4v;
        }
    }

    float* pb = part + (size_t)(s * NH1) * BATCH + (size_t)g * 64 + lane;
#pragma unroll
    for (int half = 0; half < 2; ++half) {
        const int j0 = half * 25;
        float h1p[25];
#pragma unroll
        for (int j = 0; j < 25; ++j) h1p[j] = 0.f;
#pragma unroll
        for (int ii = 0; ii < NS; ++ii) {
            const float* wrow = w1 + (size_t)(kstart + ii) * NH1 + j0;
            float c = acc[ii];
#pragma unroll
            for (int j = 0; j < 25; ++j) h1p[j] = fmaf(c, wrow[j], h1p[j]);
        }
#pragma unroll
        for (int j = 0; j < 25; ++j)
            pb[(size_t)(j0 + j) * BATCH] = h1p[j];
    }
}

__global__ void __launch_bounds__(64)
conv_fc1_k4(const float* __restrict__ x,
            const float* __restrict__ cw, const float* __restrict__ cb,
            const float* __restrict__ w1, float* __restrict__ part)
{
    __shared__ float tile[64 * 57];
    conv_fc1_body<49, 48, 14, 57, 4>(x, cw, cb, w1, part, tile);
}

__global__ void __launch_bounds__(64)
conv_fc1_k2(const float* __restrict__ x,
            const float* __restrict__ cw, const float* __restrict__ cb,
            const float* __restrict__ w1, float* __restrict__ part)
{
    __shared__ float tile[64 * 105];
    conv_fc1_body<98, 96, 26, 105, 2>(x, cw, cb, w1, part, tile);
}

// ---------------- K2: quad-split reduce + fc2 + fc3 + Procrustes ----------------
// 4 lanes per batch. 2048 blocks x 64 threads = 2048 waves = 2/SIMD on every
// SIMD (old: 512 waves = 0.5/SIMD, half the chip idle). Role r loads slices
// {r, r+4} for all 50 k (independent loads, deep MLP), quad shfl_xor reduce
// broadcasts the full presum to all 4 lanes; fc2/fc3/Jacobi run redundantly
// per quad; output writes striped by role.
template<int NSPLIT>
__global__ void __launch_bounds__(64)
tail_kernel(
    const float* __restrict__ part,
    const float* __restrict__ b1,
    const float* __restrict__ w2, const float* __restrict__ b2,
    const float* __restrict__ w3, const float* __restrict__ b3,
    float* __restrict__ out)
{
    const int t    = threadIdx.x;
    const int bid  = blockIdx.x;                    // 0..2047
    const int gidx = (bid & 7) * 256 + (bid >> 3);  // XCD-chunked, bijective
    const int bsub = t >> 2;                        // 0..15
    const int role = t & 3;
    const int b    = gidx * 16 + bsub;

    // role-partial presums for all 50 k (loads independent -> deep MLP)
    float a[NH1];
#pragma unroll
    for (int k = 0; k < NH1; ++k) a[k] = 0.f;
#pragma unroll
    for (int ss = 0; ss < (NSPLIT + 3) / 4; ++ss) {
        const int s = role + 4 * ss;
        if (s < NSPLIT) {
            const float* ps = part + (size_t)s * NH1 * BATCH + b;
#pragma unroll
            for (int k = 0; k < NH1; ++k)
                a[k] += ps[(size_t)k * BATCH];
        }
    }

    // quad reduction; every lane ends with the full sum
#pragma unroll
    for (int k = 0; k < NH1; ++k) {
        float v = a[k];
        v += __shfl_xor(v, 1, 64);
        v += __shfl_xor(v, 2, 64);
        a[k] = v;
    }

    // fc2 (redundant per quad -- those lanes were idle before)
    float h2[NH2];
#pragma unroll
    for (int j = 0; j < NH2; ++j) h2[j] = b2[j];
#pragma unroll
    for (int k = 0; k < NH1; ++k) {
        float hk = fmaxf(a[k] + b1[k], 0.f);
        const float* row = w2 + k * NH2;           // uniform -> s_load
#pragma unroll
        for (int j = 0; j < NH2; ++j) h2[j] = fmaf(hk, row[j], h2[j]);
    }
#pragma unroll
    for (int j = 0; j < NH2; ++j) h2[j] = fmaxf(h2[j], 0.f);

    // fc3 (no relu)
    float o[NOUT];
#pragma unroll
    for (int j = 0; j < NOUT; ++j) o[j] = b3[j];
#pragma unroll
    for (int k = 0; k < NH2; ++k) {
        float hk = h2[k];
        const float* row = w3 + k * NOUT;          // uniform -> s_load
#pragma unroll
        for (int j = 0; j < NOUT; ++j) o[j] = fmaf(hk, row[j], o[j]);
    }

    // ---- closest proper rotation (Davenport K-matrix, f32 Jacobi) ----
    float r00 = o[0], r01 = o[1], r02 = o[2];
    float r10 = o[3], r11 = o[4], r12 = o[5];
    float r20 = o[6], r21 = o[7], r22 = o[8];

    float A[4][4], V[4][4];
    A[0][0] = r00 + r11 + r22;
    A[1][1] = r00 - r11 - r22;
    A[2][2] = r11 - r00 - r22;
    A[3][3] = r22 - r00 - r11;
    A[0][1] = A[1][0] = r21 - r12;
    A[0][2] = A[2][0] = r02 - r20;
    A[0][3] = A[3][0] = r10 - r01;
    A[1][2] = A[2][1] = r01 + r10;
    A[1][3] = A[3][1] = r02 + r20;
    A[2][3] = A[3][2] = r12 + r21;
#pragma unroll
    for (int i = 0; i < 4; ++i)
#pragma unroll
        for (int j = 0; j < 4; ++j) V[i][j] = (i == j) ? 1.f : 0.f;

    const int pr[6][2] = {{0,1},{0,2},{0,3},{1,2},{1,3},{2,3}};
    for (int sweep = 0; sweep < 7; ++sweep) {
#pragma unroll
        for (int pi = 0; pi < 6; ++pi) {
            const int p = pr[pi][0], qq = pr[pi][1];
            float apq = A[p][qq];
            if (fabsf(apq) > 1e-20f) {
                float theta = (A[qq][qq] - A[p][p]) / (2.f * apq);
                float tt = copysignf(1.f, theta) / (fabsf(theta) + sqrtf(1.f + theta * theta));
                float c = rsqrtf(1.f + tt * tt);
                float sn = tt * c;
#pragma unroll
                for (int k = 0; k < 4; ++k) {
                    float akp = A[k][p], akq = A[k][qq];
                    A[k][p] = c * akp - sn * akq;
                    A[k][qq] = sn * akp + c * akq;
                }
#pragma unroll
                for (int k = 0; k < 4; ++k) {
                    float apk = A[p][k], aqk = A[qq][k];
                    A[p][k] = c * apk - sn * aqk;
                    A[qq][k] = sn * apk + c * aqk;
                }
#pragma unroll
                for (int k = 0; k < 4; ++k) {
                    float vkp = V[k][p], vkq = V[k][qq];
                    V[k][p] = c * vkp - sn * vkq;
                    V[k][qq] = sn * vkp + c * vkq;
                }
            }
        }
    }

    int best = 0;
    float bl = A[0][0];
#pragma unroll
    for (int i = 1; i < 4; ++i)
        if (A[i][i] > bl) { bl = A[i][i]; best = i; }

    // static-index column select (dynamic V[k][best] risks scratch demotion)
    float vsel[4];
#pragma unroll
    for (int k = 0; k < 4; ++k) {
        float v = V[k][0];
        v = (best == 1) ? V[k][1] : v;
        v = (best == 2) ? V[k][2] : v;
        v = (best == 3) ? V[k][3] : v;
        vsel[k] = v;
    }
    float vw = vsel[0], vx = vsel[1], vy = vsel[2], vz = vsel[3];
    float inv = rsqrtf(vw * vw + vx * vx + vy * vy + vz * vz);
    vw *= inv; vx *= inv; vy *= inv; vz *= inv;

    float xx = vx * vx, yy = vy * vy, zz = vz * vz;
    float xy = vx * vy, xz = vx * vz, yz = vy * vz;
    float wx = vw * vx, wy = vw * vy, wz = vw * vz;

    float res[NOUT];
    res[0]  = 1.f - 2.f * (yy + zz);
    res[1]  = 2.f * (xy - wz);
    res[2]  = 2.f * (xz + wy);
    res[3]  = 2.f * (xy + wz);
    res[4]  = 1.f - 2.f * (xx + zz);
    res[5]  = 2.f * (yz - wx);
    res[6]  = 2.f * (xz - wy);
    res[7]  = 2.f * (yz + wx);
    res[8]  = 1.f - 2.f * (xx + yy);
    res[9]  = o[9];
    res[10] = o[10];
    res[11] = o[11];
    res[12] = o[12];
    res[13] = o[13];
    res[14] = o[14];

    // role-striped writes (each element written by exactly one lane of the quad)
    float* ob = out + (size_t)b * NOUT;
#pragma unroll
    for (int j = 0; j < NOUT; ++j)
        if ((j & 3) == role) ob[j] = res[j];
}

extern "C" void kernel_launch(void* const* d_in, const int* in_sizes, int n_in,
                              void* d_out, int out_size, void* d_ws, size_t ws_size,
                              hipStream_t stream) {
    const float* x  = (const float*)d_in[0];
    const float* cw = (const float*)d_in[1];
    const float* cb = (const float*)d_in[2];
    const float* w1 = (const float*)d_in[3];
    const float* b1 = (const float*)d_in[4];
    const float* w2 = (const float*)d_in[5];
    const float* b2 = (const float*)d_in[6];
    const float* w3 = (const float*)d_in[7];
    const float* b3 = (const float*)d_in[8];
    float* outp = (float*)d_out;
    float* part = (float*)d_ws;

    const size_t need7 = (size_t)7 * NH1 * BATCH * sizeof(float);  // 45.9 MB
    const size_t need4 = (size_t)4 * NH1 * BATCH * sizeof(float);  // 26.2 MB

    if (ws_size >= need7) {
        conv_fc1_k7<<<7 * (BATCH / 64), 64, 0, stream>>>(x, cw, cb, w1, part);
        tail_kernel<7><<<BATCH / 16, 64, 0, stream>>>(part, b1, w2, b2, w3, b3, outp);
    } else if (ws_size >= need4) {
        conv_fc1_k4<<<4 * (BATCH / 64), 64, 0, stream>>>(x, cw, cb, w1, part);
        tail_kernel<4><<<BATCH / 16, 64, 0, stream>>>(part, b1, w2, b2, w3, b3, outp);
    } else {
        conv_fc1_k2<<<2 * (BATCH / 64), 64, 0, stream>>>(x, cw, cb, w1, part);
        tail_kernel<2><<<BATCH / 16, 64, 0, stream>>>(part, b1, w2, b2, w3, b3, outp);
    }
}